// Round 6
// baseline (185.078 us; speedup 1.0000x reference)
//
#include <hip/hip_runtime.h>
#include <hip/hip_bf16.h>
#include <cstdint>

typedef __attribute__((ext_vector_type(8))) __bf16 bf16x8;
typedef __attribute__((ext_vector_type(4))) float f32x4;

typedef __attribute__((address_space(1))) const void g_void;
typedef __attribute__((address_space(3))) void l_void;

__device__ __forceinline__ void gload_lds16(const void* g, void* l) {
  __builtin_amdgcn_global_load_lds((g_void*)(uintptr_t)g,
                                   (l_void*)(uint32_t)(uintptr_t)l, 16, 0, 0);
}

__device__ __forceinline__ ushort f2bf(float f) {
  union { float f; uint32_t u; } v; v.f = f;
  uint32_t r = v.u + 0x7fffu + ((v.u >> 16) & 1u);
  return (ushort)(r >> 16);
}

struct WDesc {
  const float* W[7];
  int nvec[7];
  int vcum[8];
};

// ---------- gamma = mean(|W|) + 1e-8, two-phase deterministic ----------
__global__ void absmean_partial(WDesc wd, float* __restrict__ partials) {
  __shared__ float red[256];
  const int layer = blockIdx.y;
  const float4* W = (const float4*)wd.W[layer];
  const int nv = wd.nvec[layer];
  float s = 0.f;
  for (int i = blockIdx.x * 256 + threadIdx.x; i < nv; i += gridDim.x * 256) {
    float4 w = W[i];
    s += fabsf(w.x) + fabsf(w.y) + fabsf(w.z) + fabsf(w.w);
  }
  red[threadIdx.x] = s;
  __syncthreads();
  for (int o = 128; o > 0; o >>= 1) {
    if (threadIdx.x < o) red[threadIdx.x] += red[threadIdx.x + o];
    __syncthreads();
  }
  if (threadIdx.x == 0) partials[layer * 64 + blockIdx.x] = red[0];
}

__global__ void absmean_final(WDesc wd, const float* __restrict__ partials,
                              float* __restrict__ ig) {
  const int layer = blockIdx.x;
  float v = partials[layer * 64 + threadIdx.x];
  for (int o = 32; o > 0; o >>= 1) v += __shfl_down(v, o, 64);
  if (threadIdx.x == 0) {
    float mean = v / (float)(wd.nvec[layer] * 4);
    ig[layer] = 1.0f / (mean + 1e-8f);
  }
}

// ---------- fused: ternary quantize (all layers) + concat->bf16 ----------
__global__ void prep_kernel(WDesc wd, const float* __restrict__ ig,
                            ushort* __restrict__ qw,
                            const float* __restrict__ z,
                            const float* __restrict__ att,
                            ushort* __restrict__ cat, int qblks) {
  if ((int)blockIdx.x < qblks) {
    const int v = blockIdx.x * 256 + threadIdx.x;
    if (v >= wd.vcum[7]) return;
    int layer = 0;
#pragma unroll
    for (int i = 1; i < 7; ++i) layer += (v >= wd.vcum[i]);
    const int lv = v - wd.vcum[layer];
    const float g = ig[layer];
    float4 w = ((const float4*)wd.W[layer])[lv];
    ushort4 o;
    o.x = f2bf(fmaxf(-1.f, fminf(1.f, rintf(w.x * g))));
    o.y = f2bf(fmaxf(-1.f, fminf(1.f, rintf(w.y * g))));
    o.z = f2bf(fmaxf(-1.f, fminf(1.f, rintf(w.z * g))));
    o.w = f2bf(fmaxf(-1.f, fminf(1.f, rintf(w.w * g))));
    ((ushort4*)qw)[v] = o;
  } else {
    const int tg = (blockIdx.x - qblks) * 256 + threadIdx.x;
    const int row = tg >> 8;
    const int k0 = (tg & 255) * 8;
    const float* src = (k0 < 1024) ? (z + (size_t)row * 1024 + k0)
                                   : (att + (size_t)row * 1024 + (k0 - 1024));
    float4 a = ((const float4*)src)[0];
    float4 b = ((const float4*)src)[1];
    ushort4 o0; o0.x = f2bf(a.x); o0.y = f2bf(a.y); o0.z = f2bf(a.z); o0.w = f2bf(a.w);
    ushort4 o1; o1.x = f2bf(b.x); o1.y = f2bf(b.y); o1.z = f2bf(b.z); o1.w = f2bf(b.w);
    ushort4* dst = (ushort4*)(cat + (size_t)tg * 8);
    dst[0] = o0; dst[1] = o1;
  }
}

// ---------- fast GELU (tanh form, branch-free) ----------
__device__ __forceinline__ float gelu_fast(float x) {
  float x2 = x * x;
  float u = x * fmaf(x2, 0.0356774081f, 0.7978845608f);
  float e = exp2f(u * 2.8853900818f);
  float r = __builtin_amdgcn_rcpf(e + 1.0f);
  return x - x * r;
}

#define SB0() __builtin_amdgcn_sched_barrier(0)
#define BAR() __builtin_amdgcn_s_barrier()
#define LGKM0() asm volatile("s_waitcnt lgkmcnt(0)" ::: "memory")
#define VMW(NN) asm volatile("s_waitcnt vmcnt(%0)" ::"n"(NN) : "memory")

// R5 epilogue note (applies to all GEMMs below): MFMA operands are
// SWAPPED -- acc[m][n] = mfma(bfr[n], af[m], ...). The C/D lane mapping
// transposes: lane holds C[row = ..+m*16+(lane&15)][col = ..+n*16+
// (lane>>4)*4 + j], i.e. 4 CONSECUTIVE columns -> float4/ushort4 stores
// (4x fewer store instructions than the scattered-dword layout).
// Operand fragment layouts are symmetric (same loader used for both),
// so the swap is a pure relabeling of the output.

// epilogue store helper: v = 4 consecutive-col accum values + bias4
template <bool OUT_F32>
__device__ __forceinline__ void store4(void* Cv, int N, int row, int col0,
                                       const f32x4& av, const float4& bv) {
  float g0 = gelu_fast(av[0] + bv.x);
  float g1 = gelu_fast(av[1] + bv.y);
  float g2 = gelu_fast(av[2] + bv.z);
  float g3 = gelu_fast(av[3] + bv.w);
  if (OUT_F32) {
    float4 o = {g0, g1, g2, g3};
    *(float4*)&(((float*)Cv)[(size_t)row * N + col0]) = o;
  } else {
    ushort4 o;
    o.x = f2bf(g0); o.y = f2bf(g1); o.z = f2bf(g2); o.w = f2bf(g3);
    *(ushort4*)&(((ushort*)Cv)[(size_t)row * N + col0]) = o;
  }
}

// =====================================================================
// Triple-buffered 1-barrier-per-tile GEMM: BM=256, 8 waves (2M x 4N),
// BK=64, BN in {64,128}. R0-exact schedule; R5 swapped-operand epilogue.
// =====================================================================
template <int BN, bool OUT_F32>
__global__ __launch_bounds__(512, 2)
void gemm_pipe3(const ushort* __restrict__ A, const ushort* __restrict__ Bw,
                const float* __restrict__ bias, void* __restrict__ Cv,
                int M, int N, int K) {
  constexpr int BM = 256;
  constexpr int WN = BN / 4;             // 16 or 32
  constexpr int FM = 8;
  constexpr int FN = WN / 16;            // 1 or 2
  constexpr int HM = 4;
  constexpr int HN = 1;
  constexpr int SA = 4;                  // A 64-row chunks
  constexpr int SB = BN / 64;            // B 64-row chunks (1 or 2)
  constexpr int L = SA + SB;
  constexpr int TILE_USH = (BM + BN) * 64;

  __shared__ ushort lds[3 * TILE_USH];

  const int t = threadIdx.x;
  const int lane = t & 63, wid = t >> 6;
  const int wr = wid >> 2, wc = wid & 3;
  const int l15 = lane & 15, lhi = lane >> 4;

  const int gx = gridDim.x;
  const int nwg = gx * gridDim.y;
  int lin = blockIdx.y * gx + blockIdx.x;
  lin = (lin & 7) * (nwg >> 3) + (lin >> 3);  // XCD chunked (nwg % 8 == 0)
  const int bm0 = (lin / gx) * BM, bn0 = (lin % gx) * BN;

  const int NT = K >> 6;

  const int srow = t >> 3;
  const int scol = ((t & 7) ^ ((t >> 3) & 7)) * 8;

  auto stage = [&](int tile, int buf) {
    ushort* tb = &lds[buf * TILE_USH];
    const int kt = tile * 64;
#pragma unroll
    for (int c = 0; c < SA; ++c) {
      const int lr = c * 64 + srow;
      gload_lds16(A + (size_t)(bm0 + lr) * K + kt + scol,
                  &tb[lr * 64 + (t & 7) * 8]);
    }
#pragma unroll
    for (int c = 0; c < SB; ++c) {
      const int lr = c * 64 + srow;
      gload_lds16(Bw + (size_t)(bn0 + lr) * K + kt + scol,
                  &tb[BM * 64 + lr * 64 + (t & 7) * 8]);
    }
  };

  bf16x8 a[HM][2], b[HN][2];
  f32x4 acc[FM][FN] = {};

  auto loadA = [&](const ushort* tb, int mh) {
#pragma unroll
    for (int mi = 0; mi < HM; ++mi) {
      const int row = wr * 128 + (mh * HM + mi) * 16 + l15;
#pragma unroll
      for (int kh = 0; kh < 2; ++kh)
        a[mi][kh] =
            *(const bf16x8*)&tb[row * 64 + ((kh * 4 + lhi) ^ (l15 & 7)) * 8];
    }
  };
  auto loadB = [&](const ushort* tb, int nh) {
#pragma unroll
    for (int ni = 0; ni < HN; ++ni) {
      const int row = wc * WN + (nh * HN + ni) * 16 + l15;
#pragma unroll
      for (int kh = 0; kh < 2; ++kh)
        b[ni][kh] = *(const bf16x8*)&tb[BM * 64 + row * 64 +
                                        ((kh * 4 + lhi) ^ (l15 & 7)) * 8];
    }
  };

#define MFMA_(MH, NH)                                                        \
  {                                                                          \
    __builtin_amdgcn_s_setprio(1);                                           \
    _Pragma("unroll") for (int kh = 0; kh < 2; ++kh)                         \
    _Pragma("unroll") for (int mi = 0; mi < HM; ++mi)                        \
    _Pragma("unroll") for (int ni = 0; ni < HN; ++ni)                        \
      acc[(MH) * HM + mi][(NH) * HN + ni] =                                  \
          __builtin_amdgcn_mfma_f32_16x16x32_bf16(                           \
              b[ni][kh], a[mi][kh], acc[(MH) * HM + mi][(NH) * HN + ni],     \
              0, 0, 0);                                                      \
    __builtin_amdgcn_s_setprio(0);                                           \
  }

  // prologue: stage tiles 0,1 into bufs 0,1; wait tile 0; publish.
  stage(0, 0);
  stage(1, 1);
  VMW(L);
  BAR();
  SB0();

  int buf = 0, sbuf = 2;
  for (int tt = 0; tt < NT; ++tt) {
    const bool more = (tt + 2 < NT);
    if (more) stage(tt + 2, sbuf);
    const ushort* tb = &lds[buf * TILE_USH];
    if constexpr (FN == 2) {
      loadA(tb, 0); loadB(tb, 0);
      MFMA_(0, 0);
      loadB(tb, 1);
      MFMA_(0, 1);
      loadA(tb, 1);
      MFMA_(1, 1);
      loadB(tb, 0);
      MFMA_(1, 0);
    } else {
      loadA(tb, 0); loadB(tb, 0);
      MFMA_(0, 0);
      loadA(tb, 1);
      MFMA_(1, 0);
    }
    SB0();
    if (more) { VMW(L); } else { VMW(0); }
    BAR();
    SB0();
    buf = (buf == 2) ? 0 : buf + 1;
    sbuf = (sbuf == 2) ? 0 : sbuf + 1;
  }
#undef MFMA_

#pragma unroll
  for (int m = 0; m < FM; ++m) {
    const int row = bm0 + wr * 128 + m * 16 + l15;
#pragma unroll
    for (int n = 0; n < FN; ++n) {
      const int col0 = bn0 + wc * WN + n * 16 + lhi * 4;
      const float4 bv = *(const float4*)&bias[col0];
      store4<OUT_F32>(Cv, N, row, col0, acc[m][n], bv);
    }
  }
}

// =====================================================================
// R4 deep-pipelined 8-phase GEMM (schedule unchanged; R5 epilogue).
// =====================================================================
template <bool OUT_F32>
__global__ __launch_bounds__(512, 2)
void gemm_8p2(const ushort* __restrict__ A, const ushort* __restrict__ Bw,
              const float* __restrict__ bias, void* __restrict__ Cv,
              int M, int N, int K) {
  constexpr int BM = 256;
  constexpr int BN = 256;
  constexpr int TILE_USH = (BM + BN) * 64;

  __shared__ ushort lds[2 * TILE_USH];

  const int t = threadIdx.x;
  const int lane = t & 63, wid = t >> 6;
  const int wr = wid >> 2, wc = wid & 3;
  const int l15 = lane & 15, lhi = lane >> 4;

  const int gx = gridDim.x;
  const int nwg = gx * gridDim.y;
  int lin = blockIdx.y * gx + blockIdx.x;
  lin = (lin & 7) * (nwg >> 3) + (lin >> 3);  // nwg=256, %8==0
  const int bm0 = (lin / gx) * BM, bn0 = (lin % gx) * BN;

  const int NT = K >> 6;

  const int srow = t >> 3;
  const int scol = ((t & 7) ^ ((t >> 3) & 7)) * 8;

  auto stageA = [&](ushort* tb, int kt, int h) {
#pragma unroll
    for (int c = 0; c < 2; ++c) {
      const int lr = h * 128 + c * 64 + srow;
      gload_lds16(A + (size_t)(bm0 + lr) * K + kt * 64 + scol,
                  &tb[lr * 64 + (t & 7) * 8]);
    }
  };
  auto stageB = [&](ushort* tb, int kt, int h) {
#pragma unroll
    for (int c = 0; c < 2; ++c) {
      const int lr = h * 128 + c * 64 + srow;
      gload_lds16(Bw + (size_t)(bn0 + lr) * K + kt * 64 + scol,
                  &tb[BM * 64 + lr * 64 + (t & 7) * 8]);
    }
  };

  bf16x8 a[2][4][2];   // [mh][mi][kh]
  bf16x8 b[2][2][2];   // [nh][ni][kh]
  f32x4 acc[8][4] = {};

  auto loadA = [&](const ushort* tb, int mh) {
#pragma unroll
    for (int mi = 0; mi < 4; ++mi) {
      const int row = wr * 128 + mh * 64 + mi * 16 + l15;
#pragma unroll
      for (int kh = 0; kh < 2; ++kh)
        a[mh][mi][kh] =
            *(const bf16x8*)&tb[row * 64 + ((kh * 4 + lhi) ^ (l15 & 7)) * 8];
    }
  };
  auto loadB = [&](const ushort* tb, int nh) {
#pragma unroll
    for (int ni = 0; ni < 2; ++ni) {
      const int row = wc * 64 + nh * 32 + ni * 16 + l15;
#pragma unroll
      for (int kh = 0; kh < 2; ++kh)
        b[nh][ni][kh] = *(const bf16x8*)&tb[BM * 64 + row * 64 +
                                            ((kh * 4 + lhi) ^ (l15 & 7)) * 8];
    }
  };

#define MFMA_(MH, NH)                                                        \
  {                                                                          \
    __builtin_amdgcn_s_setprio(1);                                           \
    _Pragma("unroll") for (int kh = 0; kh < 2; ++kh)                         \
    _Pragma("unroll") for (int mi = 0; mi < 4; ++mi)                         \
    _Pragma("unroll") for (int ni = 0; ni < 2; ++ni)                         \
      acc[(MH) * 4 + mi][(NH) * 2 + ni] =                                    \
          __builtin_amdgcn_mfma_f32_16x16x32_bf16(                           \
              b[(NH)][ni][kh], a[(MH)][mi][kh],                              \
              acc[(MH) * 4 + mi][(NH) * 2 + ni], 0, 0, 0);                   \
    __builtin_amdgcn_s_setprio(0);                                           \
  }

  {
    ushort* b0 = &lds[0];
    ushort* b1 = &lds[TILE_USH];
    stageA(b0, 0, 0); stageA(b0, 0, 1);
    stageB(b0, 0, 0); stageB(b0, 0, 1);
    stageA(b1, 1, 0); stageA(b1, 1, 1);
    VMW(4);
    BAR();
    SB0();
  }

  for (int J = 0; J < NT; ++J) {
    const ushort* tb = &lds[(J & 1) * TILE_USH];
    ushort* cb = &lds[(J & 1) * TILE_USH];
    ushort* sb = &lds[((J + 1) & 1) * TILE_USH];
    const bool s1 = (J + 1) < NT;
    const bool s2 = (J + 2) < NT;

    loadA(tb, 0);
    loadB(tb, 0);
    if (s1) stageB(sb, J + 1, 0);
    BAR();
    LGKM0();
    SB0();
    MFMA_(0, 0);
    SB0();
    BAR();
    SB0();

    loadA(tb, 1);
    loadB(tb, 1);
    if (s1) stageB(sb, J + 1, 1);
    BAR();
    LGKM0();
    SB0();
    MFMA_(1, 1);
    SB0();
    BAR();
    SB0();

    if (s2) stageA(cb, J + 2, 0);
    BAR();
    SB0();
    MFMA_(0, 1);
    SB0();
    BAR();
    SB0();

    if (s2) stageA(cb, J + 2, 1);
    BAR();
    SB0();
    MFMA_(1, 0);
    SB0();
    if (s2) { VMW(4); } else { VMW(0); }
    BAR();
    SB0();
  }
#undef MFMA_

#pragma unroll
  for (int m = 0; m < 8; ++m) {
    const int row = bm0 + wr * 128 + m * 16 + l15;
#pragma unroll
    for (int n = 0; n < 4; ++n) {
      const int col0 = bn0 + wc * 64 + n * 16 + lhi * 4;
      const float4 bv = *(const float4*)&bias[col0];
      store4<OUT_F32>(Cv, N, row, col0, acc[m][n], bv);
    }
  }
}

// ---------- 2-phase GEMM for small layers (R2 structure; R5 epilogue) ----------
template <int BM, int BN, bool OUT_F32>
__global__ __launch_bounds__(256, 4)
void gemm_bt_bias_gelu(const ushort* __restrict__ A, const ushort* __restrict__ Bw,
                       const float* __restrict__ bias, void* __restrict__ Cv,
                       int M, int N, int K) {
  constexpr int WTM = BM / 32;
  constexpr int WTN = BN / 32;
  __shared__ ushort As[BM * 64];
  __shared__ ushort Bs[BN * 64];
  const int t = threadIdx.x;
  const int lane = t & 63, wid = t >> 6;
  const int wr = wid >> 1, wc = wid & 1;
  const int l15 = lane & 15, lhi = lane >> 4;

  const int gx = gridDim.x;
  const int nwg = gx * gridDim.y;
  int lin = blockIdx.y * gx + blockIdx.x;
  if ((nwg & 7) == 0) lin = (lin & 7) * (nwg >> 3) + (lin >> 3);
  const int bm0 = (lin / gx) * BM, bn0 = (lin % gx) * BN;

  const ushort* Abase = A + (size_t)bm0 * K;
  const ushort* Bbase = Bw + (size_t)bn0 * K;

  f32x4 acc[WTM][WTN] = {};

  for (int kt = 0; kt < K; kt += 64) {
#pragma unroll
    for (int i = 0; i < BM / 32; ++i) {
      int c = i * 256 + t;
      int r = c >> 3, c8 = c & 7;
      gload_lds16(Abase + (size_t)r * K + kt + c8 * 8, &As[c * 8]);
    }
#pragma unroll
    for (int i = 0; i < BN / 32; ++i) {
      int c = i * 256 + t;
      int r = c >> 3, c8 = c & 7;
      gload_lds16(Bbase + (size_t)r * K + kt + c8 * 8, &Bs[c * 8]);
    }
    asm volatile("s_waitcnt vmcnt(0)" ::: "memory");
    __syncthreads();
#pragma unroll
    for (int kk = 0; kk < 64; kk += 32) {
      bf16x8 af[WTM], bfr[WTN];
#pragma unroll
      for (int m = 0; m < WTM; ++m)
        af[m] = *(const bf16x8*)&As[(wr * (BM / 2) + m * 16 + l15) * 64 + kk + lhi * 8];
#pragma unroll
      for (int n = 0; n < WTN; ++n)
        bfr[n] = *(const bf16x8*)&Bs[(wc * (BN / 2) + n * 16 + l15) * 64 + kk + lhi * 8];
#pragma unroll
      for (int m = 0; m < WTM; ++m)
#pragma unroll
        for (int n = 0; n < WTN; ++n)
          acc[m][n] = __builtin_amdgcn_mfma_f32_16x16x32_bf16(bfr[n], af[m], acc[m][n], 0, 0, 0);
    }
    __syncthreads();
  }

#pragma unroll
  for (int m = 0; m < WTM; ++m) {
    const int row = bm0 + wr * (BM / 2) + m * 16 + l15;
#pragma unroll
    for (int n = 0; n < WTN; ++n) {
      const int col0 = bn0 + wc * (BN / 2) + n * 16 + lhi * 4;
      const float4 bv = *(const float4*)&bias[col0];
      store4<OUT_F32>(Cv, N, row, col0, acc[m][n], bv);
    }
  }
}

extern "C" void kernel_launch(void* const* d_in, const int* in_sizes, int n_in,
                              void* d_out, int out_size, void* d_ws, size_t ws_size,
                              hipStream_t stream) {
  const float* z   = (const float*)d_in[0];
  const float* att = (const float*)d_in[1];
  const float* Wptr[7] = {(const float*)d_in[2],  (const float*)d_in[4],
                          (const float*)d_in[6],  (const float*)d_in[8],
                          (const float*)d_in[10], (const float*)d_in[12],
                          (const float*)d_in[14]};
  const float* bptr[7] = {(const float*)d_in[3],  (const float*)d_in[5],
                          (const float*)d_in[7],  (const float*)d_in[9],
                          (const float*)d_in[11], (const float*)d_in[13],
                          (const float*)d_in[15]};
  const int Ns[7] = {1024, 512, 256, 256, 512, 1024, 2048};
  const int Ks[7] = {2048, 1024, 512, 256, 256, 512, 1024};
  const int M = 8192;

  char* ws = (char*)d_ws;
  ushort* bufA = (ushort*)ws;
  ushort* bufB = (ushort*)(ws + 33554432);
  ushort* qw   = (ushort*)(ws + 33554432 + 16777216);
  float* partials = (float*)(ws + 33554432 + 16777216 + 11141120);
  float* ig = partials + 7 * 64;

  WDesc wd;
  int cum = 0;
  size_t qoff[7]; size_t qc = 0;
  for (int l = 0; l < 7; ++l) {
    wd.W[l] = Wptr[l];
    int nv = Ns[l] * Ks[l] / 4;
    wd.nvec[l] = nv;
    wd.vcum[l] = cum;
    cum += nv;
    qoff[l] = qc;
    qc += (size_t)Ns[l] * Ks[l];
  }
  wd.vcum[7] = cum;

  const int qblks = (cum + 255) / 256;
  absmean_partial<<<dim3(64, 7), 256, 0, stream>>>(wd, partials);
  absmean_final<<<7, 64, 0, stream>>>(wd, partials, ig);
  prep_kernel<<<qblks + 8192, 256, 0, stream>>>(wd, ig, qw, z, att, bufA, qblks);

  ushort* inb = bufA; ushort* outb = bufB;
  // L0: 8192x1024, K=2048 -> pipe3 <BN=128>, grid (8,32)=256
  gemm_pipe3<128, false><<<dim3(Ns[0] / 128, M / 256), dim3(512), 0, stream>>>(
      inb, qw + qoff[0], bptr[0], outb, M, Ns[0], Ks[0]);
  { ushort* tmp = inb; inb = outb; outb = tmp; }
  // L1: 8192x512, K=1024 -> pipe3 <BN=64>, grid (8,32)=256
  gemm_pipe3<64, false><<<dim3(Ns[1] / 64, M / 256), dim3(512), 0, stream>>>(
      inb, qw + qoff[1], bptr[1], outb, M, Ns[1], Ks[1]);
  { ushort* tmp = inb; inb = outb; outb = tmp; }
  // L2: 8192x256, K=512 -> 2-phase <64,64>
  gemm_bt_bias_gelu<64, 64, false><<<dim3(Ns[2] / 64, M / 64), 256, 0, stream>>>(
      inb, qw + qoff[2], bptr[2], outb, M, Ns[2], Ks[2]);
  { ushort* tmp = inb; inb = outb; outb = tmp; }
  // L3: 8192x256, K=256 -> 2-phase <64,64>
  gemm_bt_bias_gelu<64, 64, false><<<dim3(Ns[3] / 64, M / 64), 256, 0, stream>>>(
      inb, qw + qoff[3], bptr[3], outb, M, Ns[3], Ks[3]);
  { ushort* tmp = inb; inb = outb; outb = tmp; }
  // L4: 8192x512, K=256 -> pipe3 <BN=64>, grid (8,32)=256
  gemm_pipe3<64, false><<<dim3(Ns[4] / 64, M / 256), dim3(512), 0, stream>>>(
      inb, qw + qoff[4], bptr[4], outb, M, Ns[4], Ks[4]);
  { ushort* tmp = inb; inb = outb; outb = tmp; }
  // L5: 8192x1024, K=512 -> pipe3 <BN=128>, grid (8,32)
  gemm_pipe3<128, false><<<dim3(Ns[5] / 128, M / 256), dim3(512), 0, stream>>>(
      inb, qw + qoff[5], bptr[5], outb, M, Ns[5], Ks[5]);
  { ushort* tmp = inb; inb = outb; outb = tmp; }
  // L6: 8192x2048, K=1024 -> gemm_8p2 (R4 schedule + R5 epilogue), fp32 out.
  gemm_8p2<true><<<dim3(Ns[6] / 256, M / 256), dim3(512), 0, stream>>>(
      inb, qw + qoff[6], bptr[6], d_out, M, Ns[6], Ks[6]);
}

// Round 7
// 175.705 us; speedup vs baseline: 1.0533x; 1.0533x over previous
//
#include <hip/hip_runtime.h>
#include <hip/hip_bf16.h>
#include <cstdint>

typedef __attribute__((ext_vector_type(8))) __bf16 bf16x8;
typedef __attribute__((ext_vector_type(4))) float f32x4;

typedef __attribute__((address_space(1))) const void g_void;
typedef __attribute__((address_space(3))) void l_void;

__device__ __forceinline__ void gload_lds16(const void* g, void* l) {
  __builtin_amdgcn_global_load_lds((g_void*)(uintptr_t)g,
                                   (l_void*)(uint32_t)(uintptr_t)l, 16, 0, 0);
}

__device__ __forceinline__ ushort f2bf(float f) {
  union { float f; uint32_t u; } v; v.f = f;
  uint32_t r = v.u + 0x7fffu + ((v.u >> 16) & 1u);
  return (ushort)(r >> 16);
}

struct WDesc {
  const float* W[7];
  int nvec[7];
  int vcum[8];
};

// ---------- R6: absmean partials + concat fused in one launch ----------
// blocks [0,448): absmean partial (64 blocks x 7 layers, same partition
// as before -> bit-identical partials). blocks [448, grid): concat
// z|att -> bf16 cat, grid-stride. Independent work, overlaps the reduce.
__global__ void absmean_concat(WDesc wd, float* __restrict__ partials,
                               const float* __restrict__ z,
                               const float* __restrict__ att,
                               ushort* __restrict__ cat) {
  const int b = blockIdx.x;
  const int t = threadIdx.x;
  if (b < 448) {
    __shared__ float red[256];
    const int layer = b >> 6, blk = b & 63;
    const float4* W = (const float4*)wd.W[layer];
    const int nv = wd.nvec[layer];
    float s = 0.f;
    for (int i = blk * 256 + t; i < nv; i += 64 * 256) {
      float4 w = W[i];
      s += fabsf(w.x) + fabsf(w.y) + fabsf(w.z) + fabsf(w.w);
    }
    red[t] = s;
    __syncthreads();
    for (int o = 128; o > 0; o >>= 1) {
      if (t < o) red[t] += red[t + o];
      __syncthreads();
    }
    if (t == 0) partials[layer * 64 + blk] = red[0];
  } else {
    const int nb = gridDim.x - 448;
    for (int tg = (b - 448) * 256 + t; tg < 8192 * 256; tg += nb * 256) {
      const int row = tg >> 8;
      const int k0 = (tg & 255) * 8;
      const float* src = (k0 < 1024) ? (z + (size_t)row * 1024 + k0)
                                     : (att + (size_t)row * 1024 + (k0 - 1024));
      float4 a = ((const float4*)src)[0];
      float4 c = ((const float4*)src)[1];
      ushort4 o0; o0.x = f2bf(a.x); o0.y = f2bf(a.y); o0.z = f2bf(a.z); o0.w = f2bf(a.w);
      ushort4 o1; o1.x = f2bf(c.x); o1.y = f2bf(c.y); o1.z = f2bf(c.z); o1.w = f2bf(c.w);
      ushort4* dst = (ushort4*)(cat + (size_t)tg * 8);
      dst[0] = o0; dst[1] = o1;
    }
  }
}

__global__ void absmean_final(WDesc wd, const float* __restrict__ partials,
                              float* __restrict__ ig) {
  const int layer = blockIdx.x;
  float v = partials[layer * 64 + threadIdx.x];
  for (int o = 32; o > 0; o >>= 1) v += __shfl_down(v, o, 64);
  if (threadIdx.x == 0) {
    float mean = v / (float)(wd.nvec[layer] * 4);
    ig[layer] = 1.0f / (mean + 1e-8f);
  }
}

// ---------- ternary quantize all layers (concat moved out, R6) ----------
__global__ void quant_kernel(WDesc wd, const float* __restrict__ ig,
                             ushort* __restrict__ qw) {
  const int v = blockIdx.x * 256 + threadIdx.x;
  if (v >= wd.vcum[7]) return;
  int layer = 0;
#pragma unroll
  for (int i = 1; i < 7; ++i) layer += (v >= wd.vcum[i]);
  const int lv = v - wd.vcum[layer];
  const float g = ig[layer];
  float4 w = ((const float4*)wd.W[layer])[lv];
  ushort4 o;
  o.x = f2bf(fmaxf(-1.f, fminf(1.f, rintf(w.x * g))));
  o.y = f2bf(fmaxf(-1.f, fminf(1.f, rintf(w.y * g))));
  o.z = f2bf(fmaxf(-1.f, fminf(1.f, rintf(w.z * g))));
  o.w = f2bf(fmaxf(-1.f, fminf(1.f, rintf(w.w * g))));
  ((ushort4*)qw)[v] = o;
}

// ---------- fast GELU (tanh form, branch-free) ----------
__device__ __forceinline__ float gelu_fast(float x) {
  float x2 = x * x;
  float u = x * fmaf(x2, 0.0356774081f, 0.7978845608f);
  float e = exp2f(u * 2.8853900818f);
  float r = __builtin_amdgcn_rcpf(e + 1.0f);
  return x - x * r;
}

#define SB0() __builtin_amdgcn_sched_barrier(0)
#define BAR() __builtin_amdgcn_s_barrier()
#define VMW(NN) asm volatile("s_waitcnt vmcnt(%0)" ::"n"(NN) : "memory")

// R5 epilogue (all GEMMs): operands SWAPPED -- mfma(b, a, acc) -> lane
// holds 4 CONSECUTIVE columns -> float4/ushort4 stores.
template <bool OUT_F32>
__device__ __forceinline__ void store4(void* Cv, int N, int row, int col0,
                                       const f32x4& av, const float4& bv) {
  float g0 = gelu_fast(av[0] + bv.x);
  float g1 = gelu_fast(av[1] + bv.y);
  float g2 = gelu_fast(av[2] + bv.z);
  float g3 = gelu_fast(av[3] + bv.w);
  if (OUT_F32) {
    float4 o = {g0, g1, g2, g3};
    *(float4*)&(((float*)Cv)[(size_t)row * N + col0]) = o;
  } else {
    ushort4 o;
    o.x = f2bf(g0); o.y = f2bf(g1); o.z = f2bf(g2); o.w = f2bf(g3);
    *(ushort4*)&(((ushort*)Cv)[(size_t)row * N + col0]) = o;
  }
}

// =====================================================================
// Triple-buffered 1-barrier-per-tile GEMM: BM=256, 8 waves (2M x 4N),
// BK=64, BN in {64,128}. R6: scheduling walls stripped (no SB0, no
// LGKM0, no setprio) -- compiler emits fine-grained lgkmcnt for the
// C++ ds_reads (m141: SB0 pinning costs ~40%; m190: setprio hurts
// lockstep GEMM). Memory safety: VMW asm "memory" clobbers pin all
// LDS/global ops in program order around each barrier; triple-buffer
// gives 2-tile WAR distance.
// =====================================================================
template <int BN, bool OUT_F32>
__global__ __launch_bounds__(512, 2)
void gemm_pipe3(const ushort* __restrict__ A, const ushort* __restrict__ Bw,
                const float* __restrict__ bias, void* __restrict__ Cv,
                int M, int N, int K) {
  constexpr int BM = 256;
  constexpr int WN = BN / 4;             // 16 or 32
  constexpr int FM = 8;
  constexpr int FN = WN / 16;            // 1 or 2
  constexpr int HM = 4;
  constexpr int HN = 1;
  constexpr int SA = 4;
  constexpr int SB = BN / 64;
  constexpr int L = SA + SB;
  constexpr int TILE_USH = (BM + BN) * 64;

  __shared__ ushort lds[3 * TILE_USH];

  const int t = threadIdx.x;
  const int lane = t & 63, wid = t >> 6;
  const int wr = wid >> 2, wc = wid & 3;
  const int l15 = lane & 15, lhi = lane >> 4;

  const int gx = gridDim.x;
  const int nwg = gx * gridDim.y;
  int lin = blockIdx.y * gx + blockIdx.x;
  lin = (lin & 7) * (nwg >> 3) + (lin >> 3);  // XCD chunked (nwg % 8 == 0)
  const int bm0 = (lin / gx) * BM, bn0 = (lin % gx) * BN;

  const int NT = K >> 6;

  const int srow = t >> 3;
  const int scol = ((t & 7) ^ ((t >> 3) & 7)) * 8;

  auto stage = [&](int tile, int buf) {
    ushort* tb = &lds[buf * TILE_USH];
    const int kt = tile * 64;
#pragma unroll
    for (int c = 0; c < SA; ++c) {
      const int lr = c * 64 + srow;
      gload_lds16(A + (size_t)(bm0 + lr) * K + kt + scol,
                  &tb[lr * 64 + (t & 7) * 8]);
    }
#pragma unroll
    for (int c = 0; c < SB; ++c) {
      const int lr = c * 64 + srow;
      gload_lds16(Bw + (size_t)(bn0 + lr) * K + kt + scol,
                  &tb[BM * 64 + lr * 64 + (t & 7) * 8]);
    }
  };

  bf16x8 a[HM][2], b[HN][2];
  f32x4 acc[FM][FN] = {};

  auto loadA = [&](const ushort* tb, int mh) {
#pragma unroll
    for (int mi = 0; mi < HM; ++mi) {
      const int row = wr * 128 + (mh * HM + mi) * 16 + l15;
#pragma unroll
      for (int kh = 0; kh < 2; ++kh)
        a[mi][kh] =
            *(const bf16x8*)&tb[row * 64 + ((kh * 4 + lhi) ^ (l15 & 7)) * 8];
    }
  };
  auto loadB = [&](const ushort* tb, int nh) {
#pragma unroll
    for (int ni = 0; ni < HN; ++ni) {
      const int row = wc * WN + (nh * HN + ni) * 16 + l15;
#pragma unroll
      for (int kh = 0; kh < 2; ++kh)
        b[ni][kh] = *(const bf16x8*)&tb[BM * 64 + row * 64 +
                                        ((kh * 4 + lhi) ^ (l15 & 7)) * 8];
    }
  };

#define MFMA_(MH, NH)                                                        \
  {                                                                          \
    _Pragma("unroll") for (int kh = 0; kh < 2; ++kh)                         \
    _Pragma("unroll") for (int mi = 0; mi < HM; ++mi)                        \
    _Pragma("unroll") for (int ni = 0; ni < HN; ++ni)                        \
      acc[(MH) * HM + mi][(NH) * HN + ni] =                                  \
          __builtin_amdgcn_mfma_f32_16x16x32_bf16(                           \
              b[ni][kh], a[mi][kh], acc[(MH) * HM + mi][(NH) * HN + ni],     \
              0, 0, 0);                                                      \
  }

  stage(0, 0);
  stage(1, 1);
  VMW(L);
  BAR();

  int buf = 0, sbuf = 2;
  for (int tt = 0; tt < NT; ++tt) {
    const bool more = (tt + 2 < NT);
    if (more) stage(tt + 2, sbuf);
    const ushort* tb = &lds[buf * TILE_USH];
    if constexpr (FN == 2) {
      loadA(tb, 0); loadB(tb, 0);
      MFMA_(0, 0);
      loadB(tb, 1);
      MFMA_(0, 1);
      loadA(tb, 1);
      MFMA_(1, 1);
      loadB(tb, 0);
      MFMA_(1, 0);
    } else {
      loadA(tb, 0); loadB(tb, 0);
      MFMA_(0, 0);
      loadA(tb, 1);
      MFMA_(1, 0);
    }
    if (more) { VMW(L); } else { VMW(0); }
    BAR();
    buf = (buf == 2) ? 0 : buf + 1;
    sbuf = (sbuf == 2) ? 0 : sbuf + 1;
  }
#undef MFMA_

#pragma unroll
  for (int m = 0; m < FM; ++m) {
    const int row = bm0 + wr * 128 + m * 16 + l15;
#pragma unroll
    for (int n = 0; n < FN; ++n) {
      const int col0 = bn0 + wc * WN + n * 16 + lhi * 4;
      const float4 bv = *(const float4*)&bias[col0];
      store4<OUT_F32>(Cv, N, row, col0, acc[m][n], bv);
    }
  }
}

// =====================================================================
// R6: deep-pipelined 256^2 GEMM, 2 barriers/tile, compiler-managed lgkm.
// Per tile J: {reads A0,B0 + stage B0(J+1) + MFMA Q00; reads A1,B1 +
// stage B1(J+1) + MFMA Q11; [SB0] BAR(a)} then {stage A0,A1(J+2) into
// the now-dead tb A-region; MFMA Q01,Q10 (reg-only); VMW(4); BAR(b)}.
// Hazard ledger:
//  * RAW: VMW(4) at tile J end leaves newest 4 gload insts = A0,A1(J+2),
//    retiring B0,B1(J+1) and (from tile J-1) A0,A1(J+1); BAR(b) makes it
//    all-waves. Tile J+1's reads are covered.               [checked]
//  * WAR: stageA(J+2) writes tb's A region; every wave's tb reads have
//    consuming MFMAs before BAR(a) (compiler auto-lgkm waits), and the
//    SB0 before BAR(a) walls reads/MFMAs from sinking past.  [checked]
//  * Tail: J=NT-2 skips A-stage -> VMW(0) drains B(NT-1); J=NT-1 no-op.
//  * setprio kept (role-split structure; m218b).
// =====================================================================
template <bool OUT_F32>
__global__ __launch_bounds__(512, 2)
void gemm_8p2(const ushort* __restrict__ A, const ushort* __restrict__ Bw,
              const float* __restrict__ bias, void* __restrict__ Cv,
              int M, int N, int K) {
  constexpr int BM = 256;
  constexpr int BN = 256;
  constexpr int TILE_USH = (BM + BN) * 64;

  __shared__ ushort lds[2 * TILE_USH];

  const int t = threadIdx.x;
  const int lane = t & 63, wid = t >> 6;
  const int wr = wid >> 2, wc = wid & 3;
  const int l15 = lane & 15, lhi = lane >> 4;

  const int gx = gridDim.x;
  const int nwg = gx * gridDim.y;
  int lin = blockIdx.y * gx + blockIdx.x;
  lin = (lin & 7) * (nwg >> 3) + (lin >> 3);  // nwg=256, %8==0
  const int bm0 = (lin / gx) * BM, bn0 = (lin % gx) * BN;

  const int NT = K >> 6;

  const int srow = t >> 3;
  const int scol = ((t & 7) ^ ((t >> 3) & 7)) * 8;

  auto stageA = [&](ushort* tb, int kt, int h) {
#pragma unroll
    for (int c = 0; c < 2; ++c) {
      const int lr = h * 128 + c * 64 + srow;
      gload_lds16(A + (size_t)(bm0 + lr) * K + kt * 64 + scol,
                  &tb[lr * 64 + (t & 7) * 8]);
    }
  };
  auto stageB = [&](ushort* tb, int kt, int h) {
#pragma unroll
    for (int c = 0; c < 2; ++c) {
      const int lr = h * 128 + c * 64 + srow;
      gload_lds16(Bw + (size_t)(bn0 + lr) * K + kt * 64 + scol,
                  &tb[BM * 64 + lr * 64 + (t & 7) * 8]);
    }
  };

  bf16x8 a[2][4][2];   // [mh][mi][kh]
  bf16x8 b[2][2][2];   // [nh][ni][kh]
  f32x4 acc[8][4] = {};

  auto loadA = [&](const ushort* tb, int mh) {
#pragma unroll
    for (int mi = 0; mi < 4; ++mi) {
      const int row = wr * 128 + mh * 64 + mi * 16 + l15;
#pragma unroll
      for (int kh = 0; kh < 2; ++kh)
        a[mh][mi][kh] =
            *(const bf16x8*)&tb[row * 64 + ((kh * 4 + lhi) ^ (l15 & 7)) * 8];
    }
  };
  auto loadB = [&](const ushort* tb, int nh) {
#pragma unroll
    for (int ni = 0; ni < 2; ++ni) {
      const int row = wc * 64 + nh * 32 + ni * 16 + l15;
#pragma unroll
      for (int kh = 0; kh < 2; ++kh)
        b[nh][ni][kh] = *(const bf16x8*)&tb[BM * 64 + row * 64 +
                                            ((kh * 4 + lhi) ^ (l15 & 7)) * 8];
    }
  };

#define MFMA_(MH, NH)                                                        \
  {                                                                          \
    __builtin_amdgcn_s_setprio(1);                                           \
    _Pragma("unroll") for (int kh = 0; kh < 2; ++kh)                         \
    _Pragma("unroll") for (int mi = 0; mi < 4; ++mi)                         \
    _Pragma("unroll") for (int ni = 0; ni < 2; ++ni)                         \
      acc[(MH) * 4 + mi][(NH) * 2 + ni] =                                    \
          __builtin_amdgcn_mfma_f32_16x16x32_bf16(                           \
              b[(NH)][ni][kh], a[(MH)][mi][kh],                              \
              acc[(MH) * 4 + mi][(NH) * 2 + ni], 0, 0, 0);                   \
    __builtin_amdgcn_s_setprio(0);                                           \
  }

  // prologue: tile0 full (A0,A1,B0,B1) + tile1 A-halves; VMW(4) lands
  // tile0, leaves A0,A1(1) in flight (steady-state stream order).
  {
    ushort* b0 = &lds[0];
    ushort* b1 = &lds[TILE_USH];
    stageA(b0, 0, 0); stageA(b0, 0, 1);
    stageB(b0, 0, 0); stageB(b0, 0, 1);
    stageA(b1, 1, 0); stageA(b1, 1, 1);
    VMW(4);
    BAR();
  }

  for (int J = 0; J < NT; ++J) {
    const ushort* tb = &lds[(J & 1) * TILE_USH];
    ushort* cb = &lds[(J & 1) * TILE_USH];
    ushort* sb = &lds[((J + 1) & 1) * TILE_USH];
    const bool s1 = (J + 1) < NT;
    const bool s2 = (J + 2) < NT;

    loadA(tb, 0);
    loadB(tb, 0);
    if (s1) stageB(sb, J + 1, 0);
    MFMA_(0, 0);
    loadA(tb, 1);
    loadB(tb, 1);
    if (s1) stageB(sb, J + 1, 1);
    MFMA_(1, 1);
    SB0();   // wall: keep all tb reads + their MFMAs above BAR(a)
    BAR();   // (a) tb A-region now globally dead
    if (s2) { stageA(cb, J + 2, 0); stageA(cb, J + 2, 1); }
    MFMA_(0, 1);
    MFMA_(1, 0);
    if (s2) { VMW(4); } else { VMW(0); }
    BAR();   // (b) publish staged halves
  }
#undef MFMA_

#pragma unroll
  for (int m = 0; m < 8; ++m) {
    const int row = bm0 + wr * 128 + m * 16 + l15;
#pragma unroll
    for (int n = 0; n < 4; ++n) {
      const int col0 = bn0 + wc * 64 + n * 16 + lhi * 4;
      const float4 bv = *(const float4*)&bias[col0];
      store4<OUT_F32>(Cv, N, row, col0, acc[m][n], bv);
    }
  }
}

// ---------- 2-phase GEMM for small layers (R2 structure; R5 epilogue) ----------
template <int BM, int BN, bool OUT_F32>
__global__ __launch_bounds__(256, 4)
void gemm_bt_bias_gelu(const ushort* __restrict__ A, const ushort* __restrict__ Bw,
                       const float* __restrict__ bias, void* __restrict__ Cv,
                       int M, int N, int K) {
  constexpr int WTM = BM / 32;
  constexpr int WTN = BN / 32;
  __shared__ ushort As[BM * 64];
  __shared__ ushort Bs[BN * 64];
  const int t = threadIdx.x;
  const int lane = t & 63, wid = t >> 6;
  const int wr = wid >> 1, wc = wid & 1;
  const int l15 = lane & 15, lhi = lane >> 4;

  const int gx = gridDim.x;
  const int nwg = gx * gridDim.y;
  int lin = blockIdx.y * gx + blockIdx.x;
  if ((nwg & 7) == 0) lin = (lin & 7) * (nwg >> 3) + (lin >> 3);
  const int bm0 = (lin / gx) * BM, bn0 = (lin % gx) * BN;

  const ushort* Abase = A + (size_t)bm0 * K;
  const ushort* Bbase = Bw + (size_t)bn0 * K;

  f32x4 acc[WTM][WTN] = {};

  for (int kt = 0; kt < K; kt += 64) {
#pragma unroll
    for (int i = 0; i < BM / 32; ++i) {
      int c = i * 256 + t;
      int r = c >> 3, c8 = c & 7;
      gload_lds16(Abase + (size_t)r * K + kt + c8 * 8, &As[c * 8]);
    }
#pragma unroll
    for (int i = 0; i < BN / 32; ++i) {
      int c = i * 256 + t;
      int r = c >> 3, c8 = c & 7;
      gload_lds16(Bbase + (size_t)r * K + kt + c8 * 8, &Bs[c * 8]);
    }
    asm volatile("s_waitcnt vmcnt(0)" ::: "memory");
    __syncthreads();
#pragma unroll
    for (int kk = 0; kk < 64; kk += 32) {
      bf16x8 af[WTM], bfr[WTN];
#pragma unroll
      for (int m = 0; m < WTM; ++m)
        af[m] = *(const bf16x8*)&As[(wr * (BM / 2) + m * 16 + l15) * 64 + kk + lhi * 8];
#pragma unroll
      for (int n = 0; n < WTN; ++n)
        bfr[n] = *(const bf16x8*)&Bs[(wc * (BN / 2) + n * 16 + l15) * 64 + kk + lhi * 8];
#pragma unroll
      for (int m = 0; m < WTM; ++m)
#pragma unroll
        for (int n = 0; n < WTN; ++n)
          acc[m][n] = __builtin_amdgcn_mfma_f32_16x16x32_bf16(bfr[n], af[m], acc[m][n], 0, 0, 0);
    }
    __syncthreads();
  }

#pragma unroll
  for (int m = 0; m < WTM; ++m) {
    const int row = bm0 + wr * (BM / 2) + m * 16 + l15;
#pragma unroll
    for (int n = 0; n < WTN; ++n) {
      const int col0 = bn0 + wc * (BN / 2) + n * 16 + lhi * 4;
      const float4 bv = *(const float4*)&bias[col0];
      store4<OUT_F32>(Cv, N, row, col0, acc[m][n], bv);
    }
  }
}

extern "C" void kernel_launch(void* const* d_in, const int* in_sizes, int n_in,
                              void* d_out, int out_size, void* d_ws, size_t ws_size,
                              hipStream_t stream) {
  const float* z   = (const float*)d_in[0];
  const float* att = (const float*)d_in[1];
  const float* Wptr[7] = {(const float*)d_in[2],  (const float*)d_in[4],
                          (const float*)d_in[6],  (const float*)d_in[8],
                          (const float*)d_in[10], (const float*)d_in[12],
                          (const float*)d_in[14]};
  const float* bptr[7] = {(const float*)d_in[3],  (const float*)d_in[5],
                          (const float*)d_in[7],  (const float*)d_in[9],
                          (const float*)d_in[11], (const float*)d_in[13],
                          (const float*)d_in[15]};
  const int Ns[7] = {1024, 512, 256, 256, 512, 1024, 2048};
  const int Ks[7] = {2048, 1024, 512, 256, 256, 512, 1024};
  const int M = 8192;

  char* ws = (char*)d_ws;
  ushort* bufA = (ushort*)ws;
  ushort* bufB = (ushort*)(ws + 33554432);
  ushort* qw   = (ushort*)(ws + 33554432 + 16777216);
  float* partials = (float*)(ws + 33554432 + 16777216 + 11141120);
  float* ig = partials + 7 * 64;

  WDesc wd;
  int cum = 0;
  size_t qoff[7]; size_t qc = 0;
  for (int l = 0; l < 7; ++l) {
    wd.W[l] = Wptr[l];
    int nv = Ns[l] * Ks[l] / 4;
    wd.nvec[l] = nv;
    wd.vcum[l] = cum;
    cum += nv;
    qoff[l] = qc;
    qc += (size_t)Ns[l] * Ks[l];
  }
  wd.vcum[7] = cum;

  const int qblks = (cum + 255) / 256;
  // R6: concat overlapped with absmean partials (448 reduce + 1152 concat)
  absmean_concat<<<448 + 1152, 256, 0, stream>>>(wd, partials, z, att, bufA);
  absmean_final<<<7, 64, 0, stream>>>(wd, partials, ig);
  quant_kernel<<<qblks, 256, 0, stream>>>(wd, ig, qw);

  ushort* inb = bufA; ushort* outb = bufB;
  // L0: 8192x1024, K=2048 -> pipe3 <BN=128>, grid (8,32)=256
  gemm_pipe3<128, false><<<dim3(Ns[0] / 128, M / 256), dim3(512), 0, stream>>>(
      inb, qw + qoff[0], bptr[0], outb, M, Ns[0], Ks[0]);
  { ushort* tmp = inb; inb = outb; outb = tmp; }
  // L1: 8192x512, K=1024 -> pipe3 <BN=64>, grid (8,32)=256
  gemm_pipe3<64, false><<<dim3(Ns[1] / 64, M / 256), dim3(512), 0, stream>>>(
      inb, qw + qoff[1], bptr[1], outb, M, Ns[1], Ks[1]);
  { ushort* tmp = inb; inb = outb; outb = tmp; }
  // L2: 8192x256, K=512 -> 2-phase <64,64>
  gemm_bt_bias_gelu<64, 64, false><<<dim3(Ns[2] / 64, M / 64), 256, 0, stream>>>(
      inb, qw + qoff[2], bptr[2], outb, M, Ns[2], Ks[2]);
  { ushort* tmp = inb; inb = outb; outb = tmp; }
  // L3: 8192x256, K=256 -> 2-phase <64,64>
  gemm_bt_bias_gelu<64, 64, false><<<dim3(Ns[3] / 64, M / 64), 256, 0, stream>>>(
      inb, qw + qoff[3], bptr[3], outb, M, Ns[3], Ks[3]);
  { ushort* tmp = inb; inb = outb; outb = tmp; }
  // L4: 8192x512, K=256 -> pipe3 <BN=64>, grid (8,32)=256
  gemm_pipe3<64, false><<<dim3(Ns[4] / 64, M / 256), dim3(512), 0, stream>>>(
      inb, qw + qoff[4], bptr[4], outb, M, Ns[4], Ks[4]);
  { ushort* tmp = inb; inb = outb; outb = tmp; }
  // L5: 8192x1024, K=512 -> pipe3 <BN=128>, grid (8,32)
  gemm_pipe3<128, false><<<dim3(Ns[5] / 128, M / 256), dim3(512), 0, stream>>>(
      inb, qw + qoff[5], bptr[5], outb, M, Ns[5], Ks[5]);
  { ushort* tmp = inb; inb = outb; outb = tmp; }
  // L6: 8192x2048, K=1024 -> gemm_8p2 (R6 wall-stripped), fp32 out.
  gemm_8p2<true><<<dim3(Ns[6] / 256, M / 256), dim3(512), 0, stream>>>(
      inb, qw + qoff[6], bptr[6], d_out, M, Ns[6], Ks[6]);
}